// Round 3
// baseline (1397.772 us; speedup 1.0000x reference)
//
#include <hip/hip_runtime.h>
#include <hip/hip_bf16.h>

#define B_TOK 16384
#define D_MOD 2048
#define N_EXP 16
#define R_RK  128
#define MAXTILES 272              // ceil-aligned (B*2 + 16*127)/128 <= 272
#define MAXROWS (MAXTILES * 128)  // 34816

typedef __bf16 bf16x8 __attribute__((ext_vector_type(8)));
typedef float  f32x4  __attribute__((ext_vector_type(4)));
typedef unsigned short u16x8 __attribute__((ext_vector_type(8)));

// ---------- helpers ----------
__device__ __forceinline__ unsigned short f2bf_bits(float f) {
  unsigned u = __float_as_uint(f);
  u += 0x7fffu + ((u >> 16) & 1u);   // RNE
  return (unsigned short)(u >> 16);
}
__device__ __forceinline__ float bf2f(unsigned short b) {
  return __uint_as_float((unsigned)b << 16);
}

__device__ __forceinline__ void gl2lds16(const void* g, void* l) {
  __builtin_amdgcn_global_load_lds((__attribute__((address_space(1))) void*)(void*)g,
                                   (__attribute__((address_space(3))) void*)l, 16, 0, 0);
}

// ---------- init: counts + pad rows ----------
__global__ void init_kernel(int* counts, int* tok_row, float* w_row) {
  int i = blockIdx.x * 256 + threadIdx.x;
  if (i < N_EXP) counts[i] = 0;
  if (i < MAXROWS) { tok_row[i] = 0; w_row[i] = 0.0f; }
}

// ---------- merged f32->bf16 conversions (x, Wenc, U, V) ----------
#define CVT_N0 (B_TOK * D_MOD / 4)          // 8388608 float4s of x
#define CVT_N1 (D_MOD * D_MOD / 4)          // 1048576 Wenc
#define CVT_N2 (N_EXP * R_RK * D_MOD / 4)   // 1048576 U
#define CVT_N3 (N_EXP * D_MOD * R_RK / 4)   // 1048576 V
__global__ void cvt_all(const float* __restrict__ x, const float* __restrict__ Wenc,
                        const float* __restrict__ U, const float* __restrict__ V,
                        unsigned short* __restrict__ xb, unsigned short* __restrict__ Wencb,
                        unsigned short* __restrict__ Ub, unsigned short* __restrict__ Vb) {
  int i = blockIdx.x * 256 + threadIdx.x;
  const float4* s; ushort4* d; int j;
  if (i < CVT_N0) { s = (const float4*)x; d = (ushort4*)xb; j = i; }
  else if (i < CVT_N0 + CVT_N1) { s = (const float4*)Wenc; d = (ushort4*)Wencb; j = i - CVT_N0; }
  else if (i < CVT_N0 + CVT_N1 + CVT_N2) { s = (const float4*)U; d = (ushort4*)Ub; j = i - CVT_N0 - CVT_N1; }
  else if (i < CVT_N0 + CVT_N1 + CVT_N2 + CVT_N3) { s = (const float4*)V; d = (ushort4*)Vb; j = i - CVT_N0 - CVT_N1 - CVT_N2; }
  else return;
  float4 v = s[j];
  ushort4 o;
  o.x = f2bf_bits(v.x); o.y = f2bf_bits(v.y);
  o.z = f2bf_bits(v.z); o.w = f2bf_bits(v.w);
  d[j] = o;
}

// ---------- fp64 routing pipeline ----------
// WgEff[m][k] = sum_d Wg[m][d] * Wenc[d][k] in fp64 partials (32 d-chunks of 64)
__global__ void wgeff_partial(const float* __restrict__ Wg, const float* __restrict__ Wenc,
                              double* __restrict__ part) {
  int k = blockIdx.x * 256 + threadIdx.x;  // grid.x = 8
  int dc = blockIdx.y;                     // 0..31
  double acc[N_EXP];
#pragma unroll
  for (int m = 0; m < N_EXP; m++) acc[m] = 0.0;
  for (int d = dc * 64; d < dc * 64 + 64; ++d) {
    double we = (double)Wenc[(size_t)d * D_MOD + k];
#pragma unroll
    for (int m = 0; m < N_EXP; m++) acc[m] += (double)Wg[m * D_MOD + d] * we;
  }
#pragma unroll
  for (int m = 0; m < N_EXP; m++) part[((size_t)dc * N_EXP + m) * D_MOD + k] = acc[m];
}

// reduce partials -> WgEffF fp32 [m][k] (fp32 storage err ~1e-9; fp64 accum downstream)
__global__ void wgeff_reduce(const double* __restrict__ part, float* __restrict__ WgEffF) {
  int k = blockIdx.x * 256 + threadIdx.x;  // grid.x = 8
  int m = blockIdx.y;                      // 0..15
  double s = 0.0;
#pragma unroll
  for (int dc = 0; dc < 32; dc++) s += part[((size_t)dc * N_EXP + m) * D_MOD + k];
  WgEffF[(size_t)m * D_MOD + k] = (float)s;
}

__global__ void bias_kernel(const float* __restrict__ benc, const float* __restrict__ Wg,
                            double* __restrict__ biasd) {
  int m = blockIdx.x;
  double s = 0.0;
  for (int d = threadIdx.x; d < D_MOD; d += 256)
    s += (double)benc[d] * (double)Wg[m * D_MOD + d];
  __shared__ double red[256];
  red[threadIdx.x] = s;
  __syncthreads();
  for (int st = 128; st; st >>= 1) {
    if (threadIdx.x < st) red[threadIdx.x] += red[threadIdx.x + st];
    __syncthreads();
  }
  if (threadIdx.x == 0) biasd[m] = red[0];
}

// logits (fp64 accum) + top-2 + softmax + counts.
// 16 tokens/block (4/wave); x and WgEffF staged in LDS per 256-d chunk.
__global__ __launch_bounds__(256, 2) void routing_kernel(
    const float* __restrict__ x, const float* __restrict__ WgEffF, const double* __restrict__ biasd,
    int* __restrict__ counts, int* __restrict__ tke, float* __restrict__ tkw) {
  __shared__ float xs[16 * 256];   // 16 KB
  __shared__ float wsh[16 * 256];  // 16 KB
  const int tid = threadIdx.x;
  const int wv = tid >> 6, lane = tid & 63;
  const int b0 = blockIdx.x * 16;  // grid = 1024

  double tot[4][N_EXP];
#pragma unroll
  for (int t = 0; t < 4; t++)
#pragma unroll
    for (int m = 0; m < N_EXP; m++) tot[t][m] = 0.0;

  for (int ch = 0; ch < 8; ch++) {
    // stage 32 rows x 1KB: rows 0..15 = tokens, 16..31 = experts; 8 rows per wave
#pragma unroll
    for (int r = 0; r < 8; r++) {
      int row = wv * 8 + r;
      const float* g;
      float* l;
      if (row < 16) { g = x + (size_t)(b0 + row) * D_MOD + ch * 256; l = xs + row * 256; }
      else          { g = WgEffF + (size_t)(row - 16) * D_MOD + ch * 256; l = wsh + (row - 16) * 256; }
      gl2lds16(g + (size_t)lane * 4, l);
    }
    __syncthreads();
    for (int i = 0; i < 4; i++) {
      int dloc = i * 64 + lane;
      double xd[4];
#pragma unroll
      for (int t = 0; t < 4; t++) xd[t] = (double)xs[(wv * 4 + t) * 256 + dloc];
#pragma unroll
      for (int m = 0; m < N_EXP; m++) {
        double wd = (double)wsh[m * 256 + dloc];
#pragma unroll
        for (int t = 0; t < 4; t++) tot[t][m] = fma(xd[t], wd, tot[t][m]);
      }
    }
    __syncthreads();
  }

  // wave butterfly reduce (all lanes end with full sums)
#pragma unroll
  for (int t = 0; t < 4; t++)
#pragma unroll
    for (int m = 0; m < N_EXP; m++) {
      double v = tot[t][m];
#pragma unroll
      for (int off = 32; off; off >>= 1) v += __shfl_xor(v, off);
      tot[t][m] = v;
    }

  if (lane < 4) {
    int b = b0 + wv * 4 + lane;
    double vm[N_EXP];
#pragma unroll
    for (int m = 0; m < N_EXP; m++) {
      double v01 = (lane & 1) ? tot[1][m] : tot[0][m];
      double v23 = (lane & 1) ? tot[3][m] : tot[2][m];
      vm[m] = ((lane & 2) ? v23 : v01) + biasd[m];  // TAU = 1.0
    }
    double v1 = vm[0]; int i1 = 0;
#pragma unroll
    for (int m = 1; m < N_EXP; m++) if (vm[m] > v1) { v1 = vm[m]; i1 = m; }
    double v2 = -1e300; int i2 = 0;
#pragma unroll
    for (int m = 0; m < N_EXP; m++) if (m != i1 && vm[m] > v2) { v2 = vm[m]; i2 = m; }
    double ex = exp(v2 - v1);
    double den = 1.0 + ex;
    float w1 = (float)(1.0 / den), w2 = (float)(ex / den);
    if (!(w1 > 1e-12f)) w1 = 0.0f;
    if (!(w2 > 1e-12f)) w2 = 0.0f;
    tke[b * 2] = i1; tke[b * 2 + 1] = i2;
    tkw[b * 2] = w1; tkw[b * 2 + 1] = w2;
    atomicAdd(&counts[i1], 1);
    atomicAdd(&counts[i2], 1);
  }
}

__global__ void bases_kernel(const int* __restrict__ counts, int* cursor, int* tile2e) {
  if (threadIdx.x == 0) {
    int b = 0;
    for (int e = 0; e < N_EXP; e++) {
      cursor[e] = b;
      int nt = (counts[e] + 127) >> 7;
      for (int t = 0; t < nt; t++) tile2e[b / 128 + t] = e;
      b += nt * 128;
    }
    for (int rt = b / 128; rt < MAXTILES; rt++) tile2e[rt] = -1;
  }
}

__global__ void scatter_kernel(const int* __restrict__ tke, const float* __restrict__ tkw,
                               const float* __restrict__ gamma, int* cursor,
                               int* __restrict__ tok_row, float* __restrict__ w_row,
                               int* __restrict__ pos) {
  int b = blockIdx.x * 256 + threadIdx.x;
  if (b >= B_TOK) return;
#pragma unroll
  for (int s = 0; s < 2; s++) {
    int e = tke[b * 2 + s];
    float w = tkw[b * 2 + s] * gamma[e];
    int p = atomicAdd(&cursor[e], 1);
    tok_row[p] = b; w_row[p] = w;
    pos[b * 2 + s] = p;
  }
}

// ---------- GEMM 1: encb = bf16(x @ Wenc^T) ----------
__global__ __launch_bounds__(256) void gemm_enc(
    const unsigned short* __restrict__ A,   // x_bf16 [B, D]
    const unsigned short* __restrict__ Bm,  // Wenc_bf16 [D, D]
    unsigned short* __restrict__ encb) {    // [B, D]
  __shared__ unsigned short lA[128 * 32], lB[128 * 32];
  const int tid = threadIdx.x;
  const int wv = tid >> 6, lane = tid & 63;
  const int q = lane >> 4, l16 = lane & 15;
  const int tm = blockIdx.x, tn = blockIdx.y;

  const int srow = wv * 16 + (lane >> 2);
  const int scol = (lane & 3) * 8;
  const unsigned short* ga0 = A + (size_t)(tm * 128 + srow) * D_MOD + scol;
  const unsigned short* ga1 = ga0 + (size_t)64 * D_MOD;
  const unsigned short* gb0 = Bm + (size_t)(tn * 128 + srow) * D_MOD + scol;
  const unsigned short* gb1 = gb0 + (size_t)64 * D_MOD;
  unsigned short* la0 = &lA[(wv * 16) * 32];
  unsigned short* la1 = &lA[(wv * 16 + 64) * 32];
  unsigned short* lb0 = &lB[(wv * 16) * 32];
  unsigned short* lb1 = &lB[(wv * 16 + 64) * 32];

  const int wm = (wv & 1) * 64, wn = (wv >> 1) * 64;
  f32x4 acc[4][4] = {};

  for (int k0 = 0; k0 < D_MOD; k0 += 32) {
    gl2lds16(ga0 + k0, la0);
    gl2lds16(ga1 + k0, la1);
    gl2lds16(gb0 + k0, lb0);
    gl2lds16(gb1 + k0, lb1);
    __syncthreads();
    bf16x8 af[4], bf[4];
#pragma unroll
    for (int i = 0; i < 4; i++) af[i] = *(const bf16x8*)&lA[(wm + i * 16 + l16) * 32 + q * 8];
#pragma unroll
    for (int j = 0; j < 4; j++) bf[j] = *(const bf16x8*)&lB[(wn + j * 16 + l16) * 32 + q * 8];
#pragma unroll
    for (int i = 0; i < 4; i++)
#pragma unroll
      for (int j = 0; j < 4; j++)
        acc[i][j] = __builtin_amdgcn_mfma_f32_16x16x32_bf16(af[i], bf[j], acc[i][j], 0, 0, 0);
    __syncthreads();
  }
#pragma unroll
  for (int i = 0; i < 4; i++)
#pragma unroll
    for (int r = 0; r < 4; r++) {
      int row = tm * 128 + wm + i * 16 + q * 4 + r;
#pragma unroll
      for (int j = 0; j < 4; j++) {
        int col = tn * 128 + wn + j * 16 + l16;
        encb[(size_t)row * D_MOD + col] = f2bf_bits(acc[i][j][r]);
      }
    }
}

// ---------- GEMM 2: S = silu(enc_gathered @ U[e]^T) * (w*gamma) ----------
__global__ __launch_bounds__(256) void gemm_up(
    const unsigned short* __restrict__ encb,  // [B, D]
    const unsigned short* __restrict__ Ub,    // [M, R, D]
    const int* __restrict__ tile2e, const int* __restrict__ tok_row,
    const float* __restrict__ w_row,
    unsigned short* __restrict__ S) {         // [MAXROWS, R]
  const int rt = blockIdx.x;
  const int e = tile2e[rt];
  if (e < 0) return;
  __shared__ unsigned short lA[128 * 32], lB[128 * 32];
  const int tid = threadIdx.x;
  const int wv = tid >> 6, lane = tid & 63;
  const int q = lane >> 4, l16 = lane & 15;

  const int srow = wv * 16 + (lane >> 2);
  const int scol = (lane & 3) * 8;
  const int tok0 = tok_row[rt * 128 + srow];
  const int tok1 = tok_row[rt * 128 + srow + 64];
  const unsigned short* ga0 = encb + (size_t)tok0 * D_MOD + scol;
  const unsigned short* ga1 = encb + (size_t)tok1 * D_MOD + scol;
  const unsigned short* gbase = Ub + (size_t)e * R_RK * D_MOD;
  const unsigned short* gb0 = gbase + (size_t)srow * D_MOD + scol;
  const unsigned short* gb1 = gb0 + (size_t)64 * D_MOD;
  unsigned short* la0 = &lA[(wv * 16) * 32];
  unsigned short* la1 = &lA[(wv * 16 + 64) * 32];
  unsigned short* lb0 = &lB[(wv * 16) * 32];
  unsigned short* lb1 = &lB[(wv * 16 + 64) * 32];

  const int wm = (wv & 1) * 64, wn = (wv >> 1) * 64;
  f32x4 acc[4][4] = {};

  for (int k0 = 0; k0 < D_MOD; k0 += 32) {
    gl2lds16(ga0 + k0, la0);
    gl2lds16(ga1 + k0, la1);
    gl2lds16(gb0 + k0, lb0);
    gl2lds16(gb1 + k0, lb1);
    __syncthreads();
    bf16x8 af[4], bf[4];
#pragma unroll
    for (int i = 0; i < 4; i++) af[i] = *(const bf16x8*)&lA[(wm + i * 16 + l16) * 32 + q * 8];
#pragma unroll
    for (int j = 0; j < 4; j++) bf[j] = *(const bf16x8*)&lB[(wn + j * 16 + l16) * 32 + q * 8];
#pragma unroll
    for (int i = 0; i < 4; i++)
#pragma unroll
      for (int j = 0; j < 4; j++)
        acc[i][j] = __builtin_amdgcn_mfma_f32_16x16x32_bf16(af[i], bf[j], acc[i][j], 0, 0, 0);
    __syncthreads();
  }
#pragma unroll
  for (int i = 0; i < 4; i++)
#pragma unroll
    for (int r = 0; r < 4; r++) {
      int prow = rt * 128 + wm + i * 16 + q * 4 + r;
      float wr = w_row[prow];  // pad rows have w=0 -> write 0
#pragma unroll
      for (int j = 0; j < 4; j++) {
        int col = wn + j * 16 + l16;
        float v = acc[i][j][r];
        float sw = (v / (1.0f + __expf(-v))) * wr;
        S[(size_t)prow * R_RK + col] = f2bf_bits(sw);
      }
    }
}

// ---------- GEMM 3: Drows = S @ V[e]^T (dense per-slot delta rows, bf16) ----------
__global__ __launch_bounds__(256) void gemm_down(
    const unsigned short* __restrict__ S,   // [MAXROWS, R]
    const unsigned short* __restrict__ Vb,  // [M, D, R]
    const int* __restrict__ tile2e,
    unsigned short* __restrict__ Drows) {   // [MAXROWS, D]
  const int rt = blockIdx.x, ct = blockIdx.y;
  const int e = tile2e[rt];
  if (e < 0) return;
  __shared__ unsigned short lA[128 * 32], lB[128 * 32];
  const int tid = threadIdx.x;
  const int wv = tid >> 6, lane = tid & 63;
  const int q = lane >> 4, l16 = lane & 15;

  const int srow = wv * 16 + (lane >> 2);
  const int scol = (lane & 3) * 8;
  const unsigned short* ga0 = S + (size_t)(rt * 128 + srow) * R_RK + scol;
  const unsigned short* ga1 = ga0 + (size_t)64 * R_RK;
  const unsigned short* gb0 = Vb + ((size_t)e * D_MOD + ct * 128 + srow) * R_RK + scol;
  const unsigned short* gb1 = gb0 + (size_t)64 * R_RK;
  unsigned short* la0 = &lA[(wv * 16) * 32];
  unsigned short* la1 = &lA[(wv * 16 + 64) * 32];
  unsigned short* lb0 = &lB[(wv * 16) * 32];
  unsigned short* lb1 = &lB[(wv * 16 + 64) * 32];

  const int wm = (wv & 1) * 64, wn = (wv >> 1) * 64;
  f32x4 acc[4][4] = {};

  for (int k0 = 0; k0 < R_RK; k0 += 32) {
    gl2lds16(ga0 + k0, la0);
    gl2lds16(ga1 + k0, la1);
    gl2lds16(gb0 + k0, lb0);
    gl2lds16(gb1 + k0, lb1);
    __syncthreads();
    bf16x8 af[4], bf[4];
#pragma unroll
    for (int i = 0; i < 4; i++) af[i] = *(const bf16x8*)&lA[(wm + i * 16 + l16) * 32 + q * 8];
#pragma unroll
    for (int j = 0; j < 4; j++) bf[j] = *(const bf16x8*)&lB[(wn + j * 16 + l16) * 32 + q * 8];
#pragma unroll
    for (int i = 0; i < 4; i++)
#pragma unroll
      for (int j = 0; j < 4; j++)
        acc[i][j] = __builtin_amdgcn_mfma_f32_16x16x32_bf16(af[i], bf[j], acc[i][j], 0, 0, 0);
    __syncthreads();
  }
#pragma unroll
  for (int i = 0; i < 4; i++)
#pragma unroll
    for (int r = 0; r < 4; r++) {
      int prow = rt * 128 + wm + i * 16 + q * 4 + r;
      size_t obase = (size_t)prow * D_MOD + ct * 128 + wn;
#pragma unroll
      for (int j = 0; j < 4; j++)
        Drows[obase + j * 16 + l16] = f2bf_bits(acc[i][j][r]);
    }
}

// ---------- gather: out[b] = enc[b] + Drows[pos(b,0)] + Drows[pos(b,1)] ----------
__global__ __launch_bounds__(256) void gather_kernel(
    const unsigned short* __restrict__ encb, const unsigned short* __restrict__ Drows,
    const int* __restrict__ pos, float* __restrict__ out) {
  int b = blockIdx.x;
  int t = threadIdx.x;           // cols t*8 .. t*8+7
  int p0 = pos[b * 2], p1 = pos[b * 2 + 1];
  u16x8 e8 = *(const u16x8*)(encb + (size_t)b * D_MOD + t * 8);
  u16x8 d0 = *(const u16x8*)(Drows + (size_t)p0 * D_MOD + t * 8);
  u16x8 d1 = *(const u16x8*)(Drows + (size_t)p1 * D_MOD + t * 8);
  float o[8];
#pragma unroll
  for (int k = 0; k < 8; k++) o[k] = bf2f(e8[k]) + bf2f(d0[k]) + bf2f(d1[k]);
  float4* op = (float4*)(out + (size_t)b * D_MOD + t * 8);
  op[0] = make_float4(o[0], o[1], o[2], o[3]);
  op[1] = make_float4(o[4], o[5], o[6], o[7]);
}

// ---------- launch ----------
extern "C" void kernel_launch(void* const* d_in, const int* in_sizes, int n_in,
                              void* d_out, int out_size, void* d_ws, size_t ws_size,
                              hipStream_t stream) {
  const float* x    = (const float*)d_in[0];
  const float* Wenc = (const float*)d_in[1];
  const float* benc = (const float*)d_in[2];
  const float* Wg   = (const float*)d_in[3];
  const float* U    = (const float*)d_in[4];
  const float* V    = (const float*)d_in[5];
  const float* gamma= (const float*)d_in[6];
  float* out = (float*)d_out;

  char* ws = (char*)d_ws;
  size_t off = 0;
  auto alloc = [&](size_t bytes) { size_t o = off; off = (off + bytes + 255) & ~(size_t)255; return o; };
  unsigned short* xb    = (unsigned short*)(ws + alloc((size_t)B_TOK * D_MOD * 2));
  unsigned short* Wencb = (unsigned short*)(ws + alloc((size_t)D_MOD * D_MOD * 2));
  unsigned short* encb  = (unsigned short*)(ws + alloc((size_t)B_TOK * D_MOD * 2));
  unsigned short* Ub    = (unsigned short*)(ws + alloc((size_t)N_EXP * R_RK * D_MOD * 2));
  unsigned short* Vb    = (unsigned short*)(ws + alloc((size_t)N_EXP * D_MOD * R_RK * 2));
  float*  WgEffF = (float*)(ws + alloc((size_t)N_EXP * D_MOD * 4));
  double* part  = (double*)(ws + alloc((size_t)32 * N_EXP * D_MOD * 8));
  double* biasd = (double*)(ws + alloc(N_EXP * 8));
  int* counts   = (int*)(ws + alloc(64));
  int* cursor   = (int*)(ws + alloc(64));
  int* tile2e   = (int*)(ws + alloc(MAXTILES * 4));
  int* tke      = (int*)(ws + alloc((size_t)B_TOK * 2 * 4));
  float* tkw    = (float*)(ws + alloc((size_t)B_TOK * 2 * 4));
  int* pos      = (int*)(ws + alloc((size_t)B_TOK * 2 * 4));
  int* tok_row  = (int*)(ws + alloc((size_t)MAXROWS * 4));
  float* w_row  = (float*)(ws + alloc((size_t)MAXROWS * 4));
  unsigned short* S = (unsigned short*)(ws + alloc((size_t)MAXROWS * R_RK * 2));
  unsigned short* Drows = (unsigned short*)(ws + alloc((size_t)MAXROWS * D_MOD * 2));
  (void)ws_size; (void)in_sizes; (void)n_in; (void)out_size;

  init_kernel<<<(MAXROWS + 255) / 256, 256, 0, stream>>>(counts, tok_row, w_row);

  int cvt_total = CVT_N0 + CVT_N1 + CVT_N2 + CVT_N3;
  cvt_all<<<(cvt_total + 255) / 256, 256, 0, stream>>>(x, Wenc, U, V, xb, Wencb, Ub, Vb);

  wgeff_partial<<<dim3(8, 32), 256, 0, stream>>>(Wg, Wenc, part);
  wgeff_reduce<<<dim3(8, N_EXP), 256, 0, stream>>>(part, WgEffF);
  bias_kernel<<<N_EXP, 256, 0, stream>>>(benc, Wg, biasd);

  routing_kernel<<<B_TOK / 16, 256, 0, stream>>>(x, WgEffF, biasd, counts, tke, tkw);
  bases_kernel<<<1, 64, 0, stream>>>(counts, cursor, tile2e);
  scatter_kernel<<<(B_TOK + 255) / 256, 256, 0, stream>>>(tke, tkw, gamma, cursor, tok_row, w_row, pos);

  gemm_enc<<<dim3(B_TOK / 128, D_MOD / 128), 256, 0, stream>>>(xb, Wencb, encb);
  gemm_up<<<MAXTILES, 256, 0, stream>>>(encb, Ub, tile2e, tok_row, w_row, S);
  gemm_down<<<dim3(MAXTILES, D_MOD / 128), 256, 0, stream>>>(S, Vb, tile2e, Drows);
  gather_kernel<<<B_TOK, 256, 0, stream>>>(encb, Drows, pos, out);
}

// Round 4
// 958.558 us; speedup vs baseline: 1.4582x; 1.4582x over previous
//
#include <hip/hip_runtime.h>
#include <hip/hip_bf16.h>

#define B_TOK 16384
#define D_MOD 2048
#define N_EXP 16
#define R_RK  128
#define MAXTILES 272              // ceil-aligned (B*2 + 16*127)/128 <= 272
#define MAXROWS (MAXTILES * 128)  // 34816

typedef __bf16 bf16x8 __attribute__((ext_vector_type(8)));
typedef float  f32x4  __attribute__((ext_vector_type(4)));
typedef unsigned short u16x8 __attribute__((ext_vector_type(8)));

// ---------- helpers ----------
__device__ __forceinline__ unsigned short f2bf_bits(float f) {
  unsigned u = __float_as_uint(f);
  u += 0x7fffu + ((u >> 16) & 1u);   // RNE
  return (unsigned short)(u >> 16);
}
__device__ __forceinline__ float bf2f(unsigned short b) {
  return __uint_as_float((unsigned)b << 16);
}

__device__ __forceinline__ void gl2lds16(const void* g, void* l) {
  __builtin_amdgcn_global_load_lds((__attribute__((address_space(1))) void*)(void*)g,
                                   (__attribute__((address_space(3))) void*)l, 16, 0, 0);
}

// ---------- init: counts + pad rows ----------
__global__ void init_kernel(int* counts, int* tok_row, float* w_row) {
  int i = blockIdx.x * 256 + threadIdx.x;
  if (i < N_EXP) counts[i] = 0;
  if (i < MAXROWS) { tok_row[i] = 0; w_row[i] = 0.0f; }
}

// ---------- merged f32->bf16 conversions (x, Wenc, U, V) ----------
#define CVT_N0 (B_TOK * D_MOD / 4)          // 8388608 float4s of x
#define CVT_N1 (D_MOD * D_MOD / 4)          // 1048576 Wenc
#define CVT_N2 (N_EXP * R_RK * D_MOD / 4)   // 1048576 U
#define CVT_N3 (N_EXP * D_MOD * R_RK / 4)   // 1048576 V
__global__ void cvt_all(const float* __restrict__ x, const float* __restrict__ Wenc,
                        const float* __restrict__ U, const float* __restrict__ V,
                        unsigned short* __restrict__ xb, unsigned short* __restrict__ Wencb,
                        unsigned short* __restrict__ Ub, unsigned short* __restrict__ Vb) {
  int i = blockIdx.x * 256 + threadIdx.x;
  const float4* s; ushort4* d; int j;
  if (i < CVT_N0) { s = (const float4*)x; d = (ushort4*)xb; j = i; }
  else if (i < CVT_N0 + CVT_N1) { s = (const float4*)Wenc; d = (ushort4*)Wencb; j = i - CVT_N0; }
  else if (i < CVT_N0 + CVT_N1 + CVT_N2) { s = (const float4*)U; d = (ushort4*)Ub; j = i - CVT_N0 - CVT_N1; }
  else if (i < CVT_N0 + CVT_N1 + CVT_N2 + CVT_N3) { s = (const float4*)V; d = (ushort4*)Vb; j = i - CVT_N0 - CVT_N1 - CVT_N2; }
  else return;
  float4 v = s[j];
  ushort4 o;
  o.x = f2bf_bits(v.x); o.y = f2bf_bits(v.y);
  o.z = f2bf_bits(v.z); o.w = f2bf_bits(v.w);
  d[j] = o;
}

// ---------- fp64 routing pipeline ----------
// WgEff[m][k] = sum_d Wg[m][d] * Wenc[d][k] in fp64 partials (32 d-chunks of 64)
__global__ void wgeff_partial(const float* __restrict__ Wg, const float* __restrict__ Wenc,
                              double* __restrict__ part) {
  int k = blockIdx.x * 256 + threadIdx.x;  // grid.x = 8
  int dc = blockIdx.y;                     // 0..31
  double acc[N_EXP];
#pragma unroll
  for (int m = 0; m < N_EXP; m++) acc[m] = 0.0;
  for (int d = dc * 64; d < dc * 64 + 64; ++d) {
    double we = (double)Wenc[(size_t)d * D_MOD + k];
#pragma unroll
    for (int m = 0; m < N_EXP; m++) acc[m] += (double)Wg[m * D_MOD + d] * we;
  }
#pragma unroll
  for (int m = 0; m < N_EXP; m++) part[((size_t)dc * N_EXP + m) * D_MOD + k] = acc[m];
}

// reduce partials -> WgEffF fp32 [m][k] (fp32 storage err ~1e-9; fp64 accum downstream)
__global__ void wgeff_reduce(const double* __restrict__ part, float* __restrict__ WgEffF) {
  int k = blockIdx.x * 256 + threadIdx.x;  // grid.x = 8
  int m = blockIdx.y;                      // 0..15
  double s = 0.0;
#pragma unroll
  for (int dc = 0; dc < 32; dc++) s += part[((size_t)dc * N_EXP + m) * D_MOD + k];
  WgEffF[(size_t)m * D_MOD + k] = (float)s;
}

__global__ void bias_kernel(const float* __restrict__ benc, const float* __restrict__ Wg,
                            double* __restrict__ biasd) {
  int m = blockIdx.x;
  double s = 0.0;
  for (int d = threadIdx.x; d < D_MOD; d += 256)
    s += (double)benc[d] * (double)Wg[m * D_MOD + d];
  __shared__ double red[256];
  red[threadIdx.x] = s;
  __syncthreads();
  for (int st = 128; st; st >>= 1) {
    if (threadIdx.x < st) red[threadIdx.x] += red[threadIdx.x + st];
    __syncthreads();
  }
  if (threadIdx.x == 0) biasd[m] = red[0];
}

// logits (fp64 accum) + top-2 + softmax + counts.
// 8 tokens/block, 2 per wave (64 VGPRs of fp64 acc -- the proven no-spill point).
// x and WgEffF staged in LDS per 256-d chunk via global_load_lds.
__global__ __launch_bounds__(256, 1) void routing_kernel(
    const float* __restrict__ x, const float* __restrict__ WgEffF, const double* __restrict__ biasd,
    int* __restrict__ counts, int* __restrict__ tke, float* __restrict__ tkw) {
  __shared__ float xs[8 * 256];    // 8 KB
  __shared__ float wsh[16 * 256];  // 16 KB
  const int tid = threadIdx.x;
  const int wv = tid >> 6, lane = tid & 63;
  const int b0 = blockIdx.x * 8;   // grid = 2048

  double tot0[N_EXP], tot1[N_EXP];
#pragma unroll
  for (int m = 0; m < N_EXP; m++) { tot0[m] = 0.0; tot1[m] = 0.0; }

  for (int ch = 0; ch < 8; ch++) {
    // stage 24 rows x 1KB: rows 0..7 = tokens, 8..23 = experts; 6 rows per wave
#pragma unroll
    for (int r = 0; r < 6; r++) {
      int row = wv * 6 + r;
      const float* g;
      float* l;
      if (row < 8) { g = x + (size_t)(b0 + row) * D_MOD + ch * 256; l = xs + row * 256; }
      else         { g = WgEffF + (size_t)(row - 8) * D_MOD + ch * 256; l = wsh + (row - 8) * 256; }
      gl2lds16(g + (size_t)lane * 4, l);
    }
    __syncthreads();
#pragma unroll
    for (int i = 0; i < 4; i++) {
      int dloc = i * 64 + lane;
      double x0 = (double)xs[(wv * 2 + 0) * 256 + dloc];
      double x1 = (double)xs[(wv * 2 + 1) * 256 + dloc];
#pragma unroll
      for (int m = 0; m < N_EXP; m++) {
        double wd = (double)wsh[m * 256 + dloc];
        tot0[m] = fma(x0, wd, tot0[m]);
        tot1[m] = fma(x1, wd, tot1[m]);
      }
    }
    __syncthreads();
  }

  // wave butterfly reduce (all lanes end with full sums)
#pragma unroll
  for (int m = 0; m < N_EXP; m++) {
    double v0 = tot0[m], v1 = tot1[m];
#pragma unroll
    for (int off = 32; off; off >>= 1) { v0 += __shfl_xor(v0, off); v1 += __shfl_xor(v1, off); }
    tot0[m] = v0; tot1[m] = v1;
  }

  if (lane < 2) {
    int b = b0 + wv * 2 + lane;
    double vm[N_EXP];
#pragma unroll
    for (int m = 0; m < N_EXP; m++) vm[m] = (lane ? tot1[m] : tot0[m]) + biasd[m];  // TAU = 1.0
    double v1 = vm[0]; int i1 = 0;
#pragma unroll
    for (int m = 1; m < N_EXP; m++) if (vm[m] > v1) { v1 = vm[m]; i1 = m; }
    double v2 = -1e300; int i2 = 0;
#pragma unroll
    for (int m = 0; m < N_EXP; m++) if (m != i1 && vm[m] > v2) { v2 = vm[m]; i2 = m; }
    double ex = exp(v2 - v1);
    double den = 1.0 + ex;
    float w1 = (float)(1.0 / den), w2 = (float)(ex / den);
    if (!(w1 > 1e-12f)) w1 = 0.0f;
    if (!(w2 > 1e-12f)) w2 = 0.0f;
    tke[b * 2] = i1; tke[b * 2 + 1] = i2;
    tkw[b * 2] = w1; tkw[b * 2 + 1] = w2;
    atomicAdd(&counts[i1], 1);
    atomicAdd(&counts[i2], 1);
  }
}

__global__ void bases_kernel(const int* __restrict__ counts, int* cursor, int* tile2e) {
  if (threadIdx.x == 0) {
    int b = 0;
    for (int e = 0; e < N_EXP; e++) {
      cursor[e] = b;
      int nt = (counts[e] + 127) >> 7;
      for (int t = 0; t < nt; t++) tile2e[b / 128 + t] = e;
      b += nt * 128;
    }
    for (int rt = b / 128; rt < MAXTILES; rt++) tile2e[rt] = -1;
  }
}

__global__ void scatter_kernel(const int* __restrict__ tke, const float* __restrict__ tkw,
                               const float* __restrict__ gamma, int* cursor,
                               int* __restrict__ tok_row, float* __restrict__ w_row,
                               int* __restrict__ pos) {
  int b = blockIdx.x * 256 + threadIdx.x;
  if (b >= B_TOK) return;
#pragma unroll
  for (int s = 0; s < 2; s++) {
    int e = tke[b * 2 + s];
    float w = tkw[b * 2 + s] * gamma[e];
    int p = atomicAdd(&cursor[e], 1);
    tok_row[p] = b; w_row[p] = w;
    pos[b * 2 + s] = p;
  }
}

// ---------- GEMM 1: encb = bf16(x @ Wenc^T) ----------
__global__ __launch_bounds__(256) void gemm_enc(
    const unsigned short* __restrict__ A,   // x_bf16 [B, D]
    const unsigned short* __restrict__ Bm,  // Wenc_bf16 [D, D]
    unsigned short* __restrict__ encb) {    // [B, D]
  __shared__ unsigned short lA[128 * 32], lB[128 * 32];
  const int tid = threadIdx.x;
  const int wv = tid >> 6, lane = tid & 63;
  const int q = lane >> 4, l16 = lane & 15;
  const int tm = blockIdx.x, tn = blockIdx.y;

  const int srow = wv * 16 + (lane >> 2);
  const int scol = (lane & 3) * 8;
  const unsigned short* ga0 = A + (size_t)(tm * 128 + srow) * D_MOD + scol;
  const unsigned short* ga1 = ga0 + (size_t)64 * D_MOD;
  const unsigned short* gb0 = Bm + (size_t)(tn * 128 + srow) * D_MOD + scol;
  const unsigned short* gb1 = gb0 + (size_t)64 * D_MOD;
  unsigned short* la0 = &lA[(wv * 16) * 32];
  unsigned short* la1 = &lA[(wv * 16 + 64) * 32];
  unsigned short* lb0 = &lB[(wv * 16) * 32];
  unsigned short* lb1 = &lB[(wv * 16 + 64) * 32];

  const int wm = (wv & 1) * 64, wn = (wv >> 1) * 64;
  f32x4 acc[4][4] = {};

  for (int k0 = 0; k0 < D_MOD; k0 += 32) {
    gl2lds16(ga0 + k0, la0);
    gl2lds16(ga1 + k0, la1);
    gl2lds16(gb0 + k0, lb0);
    gl2lds16(gb1 + k0, lb1);
    __syncthreads();
    bf16x8 af[4], bf[4];
#pragma unroll
    for (int i = 0; i < 4; i++) af[i] = *(const bf16x8*)&lA[(wm + i * 16 + l16) * 32 + q * 8];
#pragma unroll
    for (int j = 0; j < 4; j++) bf[j] = *(const bf16x8*)&lB[(wn + j * 16 + l16) * 32 + q * 8];
#pragma unroll
    for (int i = 0; i < 4; i++)
#pragma unroll
      for (int j = 0; j < 4; j++)
        acc[i][j] = __builtin_amdgcn_mfma_f32_16x16x32_bf16(af[i], bf[j], acc[i][j], 0, 0, 0);
    __syncthreads();
  }
#pragma unroll
  for (int i = 0; i < 4; i++)
#pragma unroll
    for (int r = 0; r < 4; r++) {
      int row = tm * 128 + wm + i * 16 + q * 4 + r;
#pragma unroll
      for (int j = 0; j < 4; j++) {
        int col = tn * 128 + wn + j * 16 + l16;
        encb[(size_t)row * D_MOD + col] = f2bf_bits(acc[i][j][r]);
      }
    }
}

// ---------- GEMM 2: S = silu(enc_gathered @ U[e]^T) * (w*gamma) ----------
__global__ __launch_bounds__(256) void gemm_up(
    const unsigned short* __restrict__ encb,  // [B, D]
    const unsigned short* __restrict__ Ub,    // [M, R, D]
    const int* __restrict__ tile2e, const int* __restrict__ tok_row,
    const float* __restrict__ w_row,
    unsigned short* __restrict__ S) {         // [MAXROWS, R]
  const int rt = blockIdx.x;
  const int e = tile2e[rt];
  if (e < 0) return;
  __shared__ unsigned short lA[128 * 32], lB[128 * 32];
  const int tid = threadIdx.x;
  const int wv = tid >> 6, lane = tid & 63;
  const int q = lane >> 4, l16 = lane & 15;

  const int srow = wv * 16 + (lane >> 2);
  const int scol = (lane & 3) * 8;
  const int tok0 = tok_row[rt * 128 + srow];
  const int tok1 = tok_row[rt * 128 + srow + 64];
  const unsigned short* ga0 = encb + (size_t)tok0 * D_MOD + scol;
  const unsigned short* ga1 = encb + (size_t)tok1 * D_MOD + scol;
  const unsigned short* gbase = Ub + (size_t)e * R_RK * D_MOD;
  const unsigned short* gb0 = gbase + (size_t)srow * D_MOD + scol;
  const unsigned short* gb1 = gb0 + (size_t)64 * D_MOD;
  unsigned short* la0 = &lA[(wv * 16) * 32];
  unsigned short* la1 = &lA[(wv * 16 + 64) * 32];
  unsigned short* lb0 = &lB[(wv * 16) * 32];
  unsigned short* lb1 = &lB[(wv * 16 + 64) * 32];

  const int wm = (wv & 1) * 64, wn = (wv >> 1) * 64;
  f32x4 acc[4][4] = {};

  for (int k0 = 0; k0 < D_MOD; k0 += 32) {
    gl2lds16(ga0 + k0, la0);
    gl2lds16(ga1 + k0, la1);
    gl2lds16(gb0 + k0, lb0);
    gl2lds16(gb1 + k0, lb1);
    __syncthreads();
    bf16x8 af[4], bf[4];
#pragma unroll
    for (int i = 0; i < 4; i++) af[i] = *(const bf16x8*)&lA[(wm + i * 16 + l16) * 32 + q * 8];
#pragma unroll
    for (int j = 0; j < 4; j++) bf[j] = *(const bf16x8*)&lB[(wn + j * 16 + l16) * 32 + q * 8];
#pragma unroll
    for (int i = 0; i < 4; i++)
#pragma unroll
      for (int j = 0; j < 4; j++)
        acc[i][j] = __builtin_amdgcn_mfma_f32_16x16x32_bf16(af[i], bf[j], acc[i][j], 0, 0, 0);
    __syncthreads();
  }
#pragma unroll
  for (int i = 0; i < 4; i++)
#pragma unroll
    for (int r = 0; r < 4; r++) {
      int prow = rt * 128 + wm + i * 16 + q * 4 + r;
      float wr = w_row[prow];  // pad rows have w=0 -> write 0
#pragma unroll
      for (int j = 0; j < 4; j++) {
        int col = wn + j * 16 + l16;
        float v = acc[i][j][r];
        float sw = (v / (1.0f + __expf(-v))) * wr;
        S[(size_t)prow * R_RK + col] = f2bf_bits(sw);
      }
    }
}

// ---------- GEMM 3: Drows = S @ V[e]^T (dense per-slot delta rows, bf16) ----------
__global__ __launch_bounds__(256) void gemm_down(
    const unsigned short* __restrict__ S,   // [MAXROWS, R]
    const unsigned short* __restrict__ Vb,  // [M, D, R]
    const int* __restrict__ tile2e,
    unsigned short* __restrict__ Drows) {   // [MAXROWS, D]
  const int rt = blockIdx.x, ct = blockIdx.y;
  const int e = tile2e[rt];
  if (e < 0) return;
  __shared__ unsigned short lA[128 * 32], lB[128 * 32];
  const int tid = threadIdx.x;
  const int wv = tid >> 6, lane = tid & 63;
  const int q = lane >> 4, l16 = lane & 15;

  const int srow = wv * 16 + (lane >> 2);
  const int scol = (lane & 3) * 8;
  const unsigned short* ga0 = S + (size_t)(rt * 128 + srow) * R_RK + scol;
  const unsigned short* ga1 = ga0 + (size_t)64 * R_RK;
  const unsigned short* gb0 = Vb + ((size_t)e * D_MOD + ct * 128 + srow) * R_RK + scol;
  const unsigned short* gb1 = gb0 + (size_t)64 * R_RK;
  unsigned short* la0 = &lA[(wv * 16) * 32];
  unsigned short* la1 = &lA[(wv * 16 + 64) * 32];
  unsigned short* lb0 = &lB[(wv * 16) * 32];
  unsigned short* lb1 = &lB[(wv * 16 + 64) * 32];

  const int wm = (wv & 1) * 64, wn = (wv >> 1) * 64;
  f32x4 acc[4][4] = {};

  for (int k0 = 0; k0 < R_RK; k0 += 32) {
    gl2lds16(ga0 + k0, la0);
    gl2lds16(ga1 + k0, la1);
    gl2lds16(gb0 + k0, lb0);
    gl2lds16(gb1 + k0, lb1);
    __syncthreads();
    bf16x8 af[4], bf[4];
#pragma unroll
    for (int i = 0; i < 4; i++) af[i] = *(const bf16x8*)&lA[(wm + i * 16 + l16) * 32 + q * 8];
#pragma unroll
    for (int j = 0; j < 4; j++) bf[j] = *(const bf16x8*)&lB[(wn + j * 16 + l16) * 32 + q * 8];
#pragma unroll
    for (int i = 0; i < 4; i++)
#pragma unroll
      for (int j = 0; j < 4; j++)
        acc[i][j] = __builtin_amdgcn_mfma_f32_16x16x32_bf16(af[i], bf[j], acc[i][j], 0, 0, 0);
    __syncthreads();
  }
#pragma unroll
  for (int i = 0; i < 4; i++)
#pragma unroll
    for (int r = 0; r < 4; r++) {
      int prow = rt * 128 + wm + i * 16 + q * 4 + r;
      size_t obase = (size_t)prow * D_MOD + ct * 128 + wn;
#pragma unroll
      for (int j = 0; j < 4; j++)
        Drows[obase + j * 16 + l16] = f2bf_bits(acc[i][j][r]);
    }
}

// ---------- gather: out[b] = enc[b] + Drows[pos(b,0)] + Drows[pos(b,1)] ----------
__global__ __launch_bounds__(256) void gather_kernel(
    const unsigned short* __restrict__ encb, const unsigned short* __restrict__ Drows,
    const int* __restrict__ pos, float* __restrict__ out) {
  int b = blockIdx.x;
  int t = threadIdx.x;           // cols t*8 .. t*8+7
  int p0 = pos[b * 2], p1 = pos[b * 2 + 1];
  u16x8 e8 = *(const u16x8*)(encb + (size_t)b * D_MOD + t * 8);
  u16x8 d0 = *(const u16x8*)(Drows + (size_t)p0 * D_MOD + t * 8);
  u16x8 d1 = *(const u16x8*)(Drows + (size_t)p1 * D_MOD + t * 8);
  float o[8];
#pragma unroll
  for (int k = 0; k < 8; k++) o[k] = bf2f(e8[k]) + bf2f(d0[k]) + bf2f(d1[k]);
  float4* op = (float4*)(out + (size_t)b * D_MOD + t * 8);
  op[0] = make_float4(o[0], o[1], o[2], o[3]);
  op[1] = make_float4(o[4], o[5], o[6], o[7]);
}

// ---------- launch ----------
extern "C" void kernel_launch(void* const* d_in, const int* in_sizes, int n_in,
                              void* d_out, int out_size, void* d_ws, size_t ws_size,
                              hipStream_t stream) {
  const float* x    = (const float*)d_in[0];
  const float* Wenc = (const float*)d_in[1];
  const float* benc = (const float*)d_in[2];
  const float* Wg   = (const float*)d_in[3];
  const float* U    = (const float*)d_in[4];
  const float* V    = (const float*)d_in[5];
  const float* gamma= (const float*)d_in[6];
  float* out = (float*)d_out;

  char* ws = (char*)d_ws;
  size_t off = 0;
  auto alloc = [&](size_t bytes) { size_t o = off; off = (off + bytes + 255) & ~(size_t)255; return o; };
  unsigned short* xb    = (unsigned short*)(ws + alloc((size_t)B_TOK * D_MOD * 2));
  unsigned short* Wencb = (unsigned short*)(ws + alloc((size_t)D_MOD * D_MOD * 2));
  unsigned short* encb  = (unsigned short*)(ws + alloc((size_t)B_TOK * D_MOD * 2));
  unsigned short* Ub    = (unsigned short*)(ws + alloc((size_t)N_EXP * R_RK * D_MOD * 2));
  unsigned short* Vb    = (unsigned short*)(ws + alloc((size_t)N_EXP * D_MOD * R_RK * 2));
  float*  WgEffF = (float*)(ws + alloc((size_t)N_EXP * D_MOD * 4));
  double* part  = (double*)(ws + alloc((size_t)32 * N_EXP * D_MOD * 8));
  double* biasd = (double*)(ws + alloc(N_EXP * 8));
  int* counts   = (int*)(ws + alloc(64));
  int* cursor   = (int*)(ws + alloc(64));
  int* tile2e   = (int*)(ws + alloc(MAXTILES * 4));
  int* tke      = (int*)(ws + alloc((size_t)B_TOK * 2 * 4));
  float* tkw    = (float*)(ws + alloc((size_t)B_TOK * 2 * 4));
  int* pos      = (int*)(ws + alloc((size_t)B_TOK * 2 * 4));
  int* tok_row  = (int*)(ws + alloc((size_t)MAXROWS * 4));
  float* w_row  = (float*)(ws + alloc((size_t)MAXROWS * 4));
  unsigned short* S = (unsigned short*)(ws + alloc((size_t)MAXROWS * R_RK * 2));
  unsigned short* Drows = (unsigned short*)(ws + alloc((size_t)MAXROWS * D_MOD * 2));
  (void)ws_size; (void)in_sizes; (void)n_in; (void)out_size;

  init_kernel<<<(MAXROWS + 255) / 256, 256, 0, stream>>>(counts, tok_row, w_row);

  int cvt_total = CVT_N0 + CVT_N1 + CVT_N2 + CVT_N3;
  cvt_all<<<(cvt_total + 255) / 256, 256, 0, stream>>>(x, Wenc, U, V, xb, Wencb, Ub, Vb);

  wgeff_partial<<<dim3(8, 32), 256, 0, stream>>>(Wg, Wenc, part);
  wgeff_reduce<<<dim3(8, N_EXP), 256, 0, stream>>>(part, WgEffF);
  bias_kernel<<<N_EXP, 256, 0, stream>>>(benc, Wg, biasd);

  routing_kernel<<<B_TOK / 8, 256, 0, stream>>>(x, WgEffF, biasd, counts, tke, tkw);
  bases_kernel<<<1, 64, 0, stream>>>(counts, cursor, tile2e);
  scatter_kernel<<<(B_TOK + 255) / 256, 256, 0, stream>>>(tke, tkw, gamma, cursor, tok_row, w_row, pos);

  gemm_enc<<<dim3(B_TOK / 128, D_MOD / 128), 256, 0, stream>>>(xb, Wencb, encb);
  gemm_up<<<MAXTILES, 256, 0, stream>>>(encb, Ub, tile2e, tok_row, w_row, S);
  gemm_down<<<dim3(MAXTILES, D_MOD / 128), 256, 0, stream>>>(S, Vb, tile2e, Drows);
  gather_kernel<<<B_TOK, 256, 0, stream>>>(encb, Drows, pos, out);
}